// Round 10
// baseline (6624.088 us; speedup 1.0000x reference)
//
#include <hip/hip_runtime.h>

#define KSEG 10000
#define NBLK 256          // counting-sort blocks == CUs; chunk = 31250
#define HALF 5000         // bin-range phase split
#define RECMAX 17000      // LDS record capacity per phase (Binom(31250,.5): +15 sigma)
#define GBIN 8            // bins per runsort block
#define CAPE 8192         // runsort staging capacity (mean 6400, +22 sigma)

typedef unsigned long long u64;
typedef unsigned int u32;
typedef unsigned short u16;
typedef unsigned char u8;

// ---------------- fused: hist + per-block scan + LDS-staged counting scatter ----------------
__global__ __launch_bounds__(1024) void localsort_lds(const int* __restrict__ dur,
                                                      const float* __restrict__ log_h,
                                                      const int* __restrict__ events,
                                                      u64* __restrict__ S,
                                                      u16* __restrict__ Pb,
                                                      int N, int chunk) {
    __shared__ u64 rec[RECMAX];          // 136000 B (phase staging; overlaid by h32 early)
    __shared__ u32 cp[KSEG / 2];         // 20000 B packed dual-u16 cursors
    __shared__ u32 wsum[16];
    __shared__ u32 carry_s, pb_half;
    u32* h32 = (u32*)rec;                // 40000 B overlay, dead before rec is written

    int b = blockIdx.x;
    int s = b * chunk, e = min(N, s + chunk);
    int tid = threadIdx.x;
    int lane = tid & 63, wid = tid >> 6;
    int kiter = (chunk + 1023) >> 10;    // 31 for N=8M

    for (int i = tid; i < KSEG; i += 1024) h32[i] = 0;
    if (tid == 0) carry_s = 0;
    __syncthreads();

    // ---- read dur into regs + histogram ----
    int myd[32];
    for (int k = 0; k < kiter; ++k) {
        int j = s + tid + (k << 10);
        int d = -1;
        if (j < e) { d = dur[j]; atomicAdd(&h32[d], 1); }
        myd[k] = d;
    }
    __syncthreads();

    // ---- exclusive scan over KSEG bins (strips of 1024, wave-shuffle scan) ----
    for (int base = 0; base < KSEG; base += 1024) {
        int t = base + tid;
        u32 h = (t < KSEG) ? h32[t] : 0;
        u32 v = h;
        for (int off = 1; off < 64; off <<= 1) {
            u32 x = __shfl_up(v, off);
            if (lane >= off) v += x;
        }
        if (lane == 63) wsum[wid] = v;
        __syncthreads();
        if (wid == 0) {
            u32 wv = (lane < 16) ? wsum[lane] : 0;
            for (int off = 1; off < 16; off <<= 1) {
                u32 x = __shfl_up(wv, off);
                if (lane >= off) wv += x;
            }
            if (lane < 16) wsum[lane] = wv;
        }
        __syncthreads();
        u32 incl = v + ((wid > 0) ? wsum[wid - 1] : 0) + carry_s;
        u32 excl = incl - h;
        if (t < KSEG) {
            Pb[(size_t)b * (KSEG + 1) + t] = (u16)excl;
            if (!(t & 1)) cp[t >> 1] = excl | (incl << 16);  // excl_t | excl_{t+1}<<16
            if (t == HALF) pb_half = excl;                   // phase-0 element count
        }
        __syncthreads();
        if (tid == 1023) carry_s = incl;
    }
    __syncthreads();
    u32 total = carry_s;
    if (tid == 0) Pb[(size_t)b * (KSEG + 1) + KSEG] = (u16)total;
    u32 base0 = pb_half;
    __syncthreads();

    // ---- two bin-range phases: LDS scatter then coalesced dump ----
    for (int ph = 0; ph < 2; ++ph) {
        int t0 = ph ? HALF : 0;
        u32 pbase = ph ? base0 : 0;
        u32 plen = ph ? (total - base0) : base0;
        for (int k = 0; k < kiter; ++k) {
            int d = myd[k];
            if ((unsigned)(d - t0) < (unsigned)HALF) {
                int j = s + tid + (k << 10);
                u32 add = (d & 1) ? 0x10000u : 1u;
                u32 old = atomicAdd(&cp[d >> 1], add);
                u32 pos = (d & 1) ? (old >> 16) : (old & 0xffffu);
                u32 hi = ((u32)j << 1) | (u32)events[j];
                rec[pos - pbase] = ((u64)hi << 32) | (u64)__float_as_uint(log_h[j]);
            }
        }
        __syncthreads();
        for (u32 i = tid; i < plen; i += 1024) S[(size_t)s + pbase + i] = rec[i];
        __syncthreads();
    }
}

// ---------------- counts[t] = sum_b (Pb[b][t+1]-Pb[b][t]) ----------------
__global__ void colscan_counts(const u16* __restrict__ Pb, int* __restrict__ counts) {
    int t = blockIdx.x * blockDim.x + threadIdx.x;
    if (t >= KSEG) return;
    int run = 0;
    for (int b = 0; b < NBLK; ++b) {
        const u16* row = Pb + (size_t)b * (KSEG + 1);
        run += (int)row[t + 1] - (int)row[t];
    }
    counts[t] = run;
}

// ---------------- exclusive prefix scan over K bins (single block) ----------------
__global__ void scan_kernel(const int* __restrict__ counts, int* __restrict__ cum, int K) {
    __shared__ int sm[1024];
    __shared__ int carry_s;
    int tid = threadIdx.x;
    if (tid == 0) carry_s = 0;
    __syncthreads();
    for (int base = 0; base < K; base += 1024) {
        int v = (base + tid < K) ? counts[base + tid] : 0;
        sm[tid] = v;
        __syncthreads();
        for (int off = 1; off < 1024; off <<= 1) {
            int t = (tid >= off) ? sm[tid - off] : 0;
            __syncthreads();
            sm[tid] += t;
            __syncthreads();
        }
        int carry = carry_s;
        if (base + tid < K) cum[base + tid] = carry + sm[tid] - v;  // exclusive
        __syncthreads();
        if (tid == 1023) carry_s = carry + sm[1023];
        __syncthreads();
    }
    if (tid == 0) cum[K] = carry_s;
}

// ---------------- transpose Pb[NBLK][K+1] -> PbT[K+1][NBLK] ----------------
__global__ void transpose_pb(const u16* __restrict__ Pb, u16* __restrict__ PbT) {
    __shared__ u16 tile[64][65];
    int t0 = blockIdx.x * 64;
    int b0 = blockIdx.y * 64;
    int tx = threadIdx.x;        // 0..63
    int ty = threadIdx.y;        // 0..3
    for (int r = ty; r < 64; r += 4) {
        int b = b0 + r, t = t0 + tx;
        tile[r][tx] = (b < NBLK && t <= KSEG) ? Pb[(size_t)b * (KSEG + 1) + t] : (u16)0;
    }
    __syncthreads();
    for (int r = ty; r < 64; r += 4) {
        int t = t0 + r, b = b0 + tx;
        if (t <= KSEG && b < NBLK) PbT[(size_t)t * NBLK + b] = tile[tx][r];
    }
}

// ---------------- per-bin-range (GBIN bins/block): contiguous gather, sort runs, emit ----
__global__ __launch_bounds__(256) void runsort_pe3(const u64* __restrict__ S,
                                                   const int* __restrict__ cum,
                                                   const u16* __restrict__ PbT,
                                                   float* __restrict__ P,
                                                   u32* __restrict__ J,
                                                   u32* __restrict__ E2w,
                                                   u16* __restrict__ binhint,
                                                   int N, int chunk) {
    __shared__ u64 sm[CAPE];                 // 65536 B
    __shared__ int L[GBIN * 256];            // 8192 B: run lens -> dest offsets
    __shared__ u16 rows[(GBIN + 1) * 256];   // 4608 B: PbT rows
    __shared__ int cumLoc[GBIN + 1];
    __shared__ u32 bits[128];
    __shared__ int t256[256];
    __shared__ u32 wpart[4];

    int t0 = blockIdx.x * GBIN;
    int G2 = min(GBIN, KSEG - t0);
    if (G2 <= 0) return;
    int tid = threadIdx.x;
    int lane = tid & 63, wid = tid >> 6;

    for (int t = 0; t <= G2; ++t)
        rows[t * 256 + tid] = PbT[(size_t)(t0 + t) * NBLK + tid];
    if (tid <= G2) cumLoc[tid] = cum[t0 + tid];
    __syncthreads();

    int u = 0;
    while (u < G2) {
        int m = 1;
        while (u + m < G2 && cumLoc[u + m + 1] - cumLoc[u] <= CAPE) ++m;
        int aBatch = cumLoc[u];

        // ---- run lengths into L (bin-major, block-minor), pad with 0 ----
        for (int tt = 0; tt < GBIN; ++tt) {
            int v = 0;
            if (tt < m)
                v = (int)rows[(u + tt + 1) * 256 + tid] - (int)rows[(u + tt) * 256 + tid];
            L[tt * 256 + tid] = v;
        }
        __syncthreads();

        // ---- exclusive scan of 2048 entries: 8-chains + one 256-scan ----
        int r8[8];
        int base8 = tid * 8, sum8 = 0;
        for (int k = 0; k < 8; ++k) { r8[k] = sum8; sum8 += L[base8 + k]; }
        t256[tid] = sum8;
        __syncthreads();
        {
            int v = t256[tid];
            for (int off = 1; off < 64; off <<= 1) {
                int x = __shfl_up(v, off);
                if (lane >= off) v += x;
            }
            if (lane == 63) wpart[wid] = (u32)v;
            __syncthreads();
            if (tid == 0) {
                u32 run = 0;
                for (int w = 0; w < 4; ++w) { u32 tmp = wpart[w]; wpart[w] = run; run += tmp; }
            }
            __syncthreads();
            int excl = v - sum8 + (int)wpart[wid];
            for (int k = 0; k < 8; ++k) r8[k] += excl;
        }
        __syncthreads();
        for (int k = 0; k < 8; ++k) L[base8 + k] = r8[k];
        __syncthreads();

        // ---- gather my contiguous S segment + insertion-sort each run ----
        {
            const u64* src = S + (size_t)tid * chunk + (int)rows[u * 256 + tid];
            for (int tt = 0; tt < m; ++tt) {
                int l = (int)rows[(u + tt + 1) * 256 + tid] - (int)rows[(u + tt) * 256 + tid];
                int o = L[tt * 256 + tid];
                for (int i = 0; i < l; ++i) sm[o + i] = src[i];
                src += l;
                for (int i = 1; i < l; ++i) {
                    u64 key = sm[o + i];
                    int jj = o + i - 1;
                    while (jj >= o && sm[jj] > key) { sm[jj + 1] = sm[jj]; --jj; }
                    sm[jj + 1] = key;
                }
            }
        }
        __syncthreads();

        // ---- emit per bin: P (desc), J (asc), E2 bitfield, binhint ----
        for (int tt = 0; tt < m; ++tt) {
            int t = u + tt;
            int a = cumLoc[t], b = cumLoc[t + 1];
            int c = b - a;
            int lbase = a - aBatch;
            int q0 = N - b;
            int nw = (c + 31) >> 5;
            for (int k = tid; k < nw; k += 256) bits[k] = 0;
            __syncthreads();
            for (int i = tid; i < c; i += 256) {
                u64 rec = sm[lbase + i];
                P[q0 + i] = expf(__uint_as_float((u32)rec));
                J[a + i] = (u32)(rec >> 33);
                if (rec & 0x100000000ull) atomicOr(&bits[i >> 5], 1u << (i & 31));
            }
            __syncthreads();
            for (int k = tid; k < nw; k += 256) {
                u32 v = bits[k];
                if (!v) continue;
                long gb = (long)q0 + 32l * k;
                int w = (int)(gb >> 5), sh = (int)(gb & 31);
                atomicOr(&E2w[w], v << sh);
                if (sh && (v >> (32 - sh))) atomicOr(&E2w[w + 1], v >> (32 - sh));
            }
            if (tid == 0) {
                for (int k = (a + 255) >> 8; (k << 8) < b; ++k) binhint[k] = (u16)t;
            }
            __syncthreads();
        }
        u += m;
    }
}

// ---------------- segment sums (faithful cross-indexing): keyed by dur[j], summand P[j] ----
__global__ __launch_bounds__(1024) void sums3(const int* __restrict__ dur,
                                              const float* __restrict__ P,
                                              const u32* __restrict__ E2w,
                                              float* __restrict__ expg_part,
                                              u16* __restrict__ evs_part,
                                              int N, int chunk) {
    __shared__ float he[KSEG];
    __shared__ int hv[KSEG];
    for (int i = threadIdx.x; i < KSEG; i += blockDim.x) { he[i] = 0.f; hv[i] = 0; }
    __syncthreads();
    int b = blockIdx.x;
    int s = b * chunk, e = min(N, s + chunk);
    for (int j = s + threadIdx.x; j < e; j += blockDim.x) {
        int t = dur[j];
        atomicAdd(&he[t], P[j]);
        if ((E2w[j >> 5] >> (j & 31)) & 1u) atomicAdd(&hv[t], 1);
    }
    __syncthreads();
    for (int i = threadIdx.x; i < KSEG; i += blockDim.x) {
        expg_part[(size_t)b * KSEG + i] = he[i];
        evs_part[(size_t)b * KSEG + i] = (u16)hv[i];
    }
}

__global__ void reduce_sums(const float* __restrict__ expg_part,
                            const u16* __restrict__ evs_part,
                            float* __restrict__ expg, float* __restrict__ evs, int B) {
    int t = blockIdx.x * blockDim.x + threadIdx.x;
    if (t >= KSEG) return;
    float a = 0.f;
    int v = 0;
    for (int b = 0; b < B; ++b) {
        a += expg_part[(size_t)b * KSEG + t];
        v += (int)evs_part[(size_t)b * KSEG + t];
    }
    expg[t] = a;
    evs[t] = (float)v;
}

// ---------------- risk suffix-sum + baseline hazard + total events ----------------
__global__ void baseline_kernel(const float* __restrict__ expg, const float* __restrict__ evs,
                                float* __restrict__ base, float* __restrict__ ev_total, int K) {
    __shared__ float sm[1024];
    __shared__ float carry_s;
    int tid = threadIdx.x;
    if (tid == 0) carry_s = 0.f;
    float evloc = 0.f;
    __syncthreads();
    for (int b = 0; b < K; b += 1024) {
        int u = b + tid;
        int t = K - 1 - u;
        float v = 0.f, ev = 0.f;
        if (u < K) { v = expg[t]; ev = evs[t]; }
        evloc += ev;
        sm[tid] = v;
        __syncthreads();
        for (int off = 1; off < 1024; off <<= 1) {
            float x = (tid >= off) ? sm[tid - off] : 0.f;
            __syncthreads();
            sm[tid] += x;
            __syncthreads();
        }
        float carry = carry_s;
        if (u < K) {
            float risk = carry + sm[tid];  // inclusive suffix sum over bins >= t
            base[t] = (risk > 0.f) ? ev / risk : 0.f;
        }
        __syncthreads();
        if (tid == 1023) carry_s = carry + sm[1023];
        __syncthreads();
    }
    sm[tid] = evloc;
    __syncthreads();
    for (int o = 512; o > 0; o >>= 1) {
        if (tid < o) sm[tid] += sm[tid + o];
        __syncthreads();
    }
    if (tid == 0) ev_total[0] = sm[0];
}

// ---------------- MSE, flat grid-stride: (base[t(i)]*P[i] - E2bit[J[i]])^2 ----------------
__global__ __launch_bounds__(1024) void mse4(const float* __restrict__ P,
                                             const u32* __restrict__ J,
                                             const u32* __restrict__ E2w,
                                             const int* __restrict__ cum,
                                             const u16* __restrict__ binhint,
                                             const float* __restrict__ base,
                                             double* __restrict__ acc, int N) {
    int stride = gridDim.x * blockDim.x;
    double s = 0.0;
    for (int i = blockIdx.x * blockDim.x + threadIdx.x; i < N; i += stride) {
        int t = (int)binhint[i >> 8];
        while (cum[t + 1] <= i) ++t;
        u32 x = J[i];
        float ev = (float)((E2w[x >> 5] >> (x & 31)) & 1u);
        float d = base[t] * P[i] - ev;
        s += (double)d * (double)d;
    }
    __shared__ double sm[1024];
    sm[threadIdx.x] = s;
    __syncthreads();
    for (int o = 512; o > 0; o >>= 1) {
        if ((int)threadIdx.x < o) sm[threadIdx.x] += sm[threadIdx.x + o];
        __syncthreads();
    }
    if (threadIdx.x == 0) atomicAdd(acc, sm[0]);
}

__global__ void final_kernel(const double* __restrict__ acc, const float* __restrict__ ev_total,
                             float* __restrict__ out, int N) {
    out[0] = (ev_total[0] == 0.f) ? 0.0f : (float)(*acc / (double)N);
}

extern "C" void kernel_launch(void* const* d_in, const int* in_sizes, int n_in,
                              void* d_out, int out_size, void* d_ws, size_t ws_size,
                              hipStream_t stream) {
    const float* log_h = (const float*)d_in[0];
    const int* dur     = (const int*)d_in[1];
    const int* events  = (const int*)d_in[2];
    int N = in_sizes[0];
    float* out = (float*)d_out;

    char* ws = (char*)d_ws;
    size_t off = 0;
    auto alloc = [&](size_t bytes) -> char* {
        char* p = ws + off;
        off = (off + bytes + 255) & ~(size_t)255;
        return p;
    };
    double* acc  = (double*)alloc(8);
    u32*    E2w  = (u32*)alloc(((size_t)N / 32 + 2) * 4);   // event bitfield (desc-indexed)
    size_t zero_bytes = off;                                 // acc + E2w must start at 0
    float*  ev_total = (float*)alloc(4);
    int*    counts   = (int*)alloc(KSEG * 4);
    int*    cum      = (int*)alloc((KSEG + 1) * 4);
    float*  expg     = (float*)alloc(KSEG * 4);
    float*  evs      = (float*)alloc(KSEG * 4);
    float*  base     = (float*)alloc(KSEG * 4);
    u16*    binhint  = (u16*)alloc(((size_t)N / 256 + 1) * 2);
    u16*    Pb       = (u16*)alloc((size_t)NBLK * (KSEG + 1) * 2);
    u16*    PbT      = (u16*)alloc((size_t)(KSEG + 1) * NBLK * 2);
    u64*    S        = (u64*)alloc((size_t)N * 8);
    float*  P        = (float*)alloc((size_t)N * 4);
    u32*    J        = (u32*)alloc((size_t)N * 4);
    (void)ws_size;

    // sums partials alias S (dead after runsort_pe3; mse4 uses P/J, not S)
    float* expg_part = (float*)S;
    u16*   evs_part  = (u16*)((char*)S + (size_t)NBLK * KSEG * 4 + 256);

    int chunk = (N + NBLK - 1) / NBLK;   // 31250 < 65536 -> u16 offsets valid

    hipMemsetAsync(d_ws, 0, zero_bytes, stream);

    localsort_lds<<<NBLK, 1024, 0, stream>>>(dur, log_h, events, S, Pb, N, chunk);
    colscan_counts<<<(KSEG + 255) / 256, 256, 0, stream>>>(Pb, counts);
    scan_kernel<<<1, 1024, 0, stream>>>(counts, cum, KSEG);
    transpose_pb<<<dim3((KSEG + 64) / 64, NBLK / 64), dim3(64, 4), 0, stream>>>(Pb, PbT);
    runsort_pe3<<<(KSEG + GBIN - 1) / GBIN, 256, 0, stream>>>(S, cum, PbT, P, J, E2w,
                                                              binhint, N, chunk);
    sums3<<<NBLK, 1024, 0, stream>>>(dur, P, E2w, expg_part, evs_part, N, chunk);
    reduce_sums<<<(KSEG + 255) / 256, 256, 0, stream>>>(expg_part, evs_part, expg, evs, NBLK);
    baseline_kernel<<<1, 1024, 0, stream>>>(expg, evs, base, ev_total, KSEG);
    mse4<<<512, 1024, 0, stream>>>(P, J, E2w, cum, binhint, base, acc, N);
    final_kernel<<<1, 1, 0, stream>>>(acc, ev_total, out, N);
}

// Round 11
// 525.280 us; speedup vs baseline: 12.6106x; 12.6106x over previous
//
#include <hip/hip_runtime.h>

#define KSEG 10000
#define NBLK 256          // counting-sort blocks == CUs; chunk = 31250
#define HALF 5000         // bin-range phase split
#define RECMAX 17000      // LDS record capacity per phase (Binom(31250,.5): +15 sigma)
#define GBIN 8            // bins per runsort block
#define CAPE 8192         // runsort staging capacity (mean 6400, +22 sigma)

typedef unsigned long long u64;
typedef unsigned int u32;
typedef unsigned short u16;
typedef unsigned char u8;

// ---------------- fused: hist + per-block scan + LDS-staged counting scatter ----------------
__global__ __launch_bounds__(1024) void localsort_lds(const int* __restrict__ dur,
                                                      const float* __restrict__ log_h,
                                                      const int* __restrict__ events,
                                                      u64* __restrict__ S,
                                                      u16* __restrict__ Pb,
                                                      int N, int chunk) {
    __shared__ u64 rec[RECMAX];          // 136000 B (phase staging; overlaid by h32 early)
    __shared__ u32 cp[KSEG / 2];         // 20000 B packed dual-u16 cursors
    __shared__ u32 wsum[16];
    __shared__ u32 carry_s, pb_half;
    u32* h32 = (u32*)rec;                // 40000 B overlay, dead before rec is written

    int b = blockIdx.x;
    int s = b * chunk, e = min(N, s + chunk);
    int tid = threadIdx.x;
    int lane = tid & 63, wid = tid >> 6;
    int kiter = (chunk + 1023) >> 10;    // 31 for N=8M

    for (int i = tid; i < KSEG; i += 1024) h32[i] = 0;
    if (tid == 0) carry_s = 0;
    __syncthreads();

    // ---- read dur into regs + histogram ----
    int myd[32];
    for (int k = 0; k < kiter; ++k) {
        int j = s + tid + (k << 10);
        int d = -1;
        if (j < e) { d = dur[j]; atomicAdd(&h32[d], 1); }
        myd[k] = d;
    }
    __syncthreads();

    // ---- exclusive scan over KSEG bins (strips of 1024, wave-shuffle scan) ----
    for (int base = 0; base < KSEG; base += 1024) {
        int t = base + tid;
        u32 h = (t < KSEG) ? h32[t] : 0;
        u32 v = h;
        for (int off = 1; off < 64; off <<= 1) {
            u32 x = __shfl_up(v, off);
            if (lane >= off) v += x;
        }
        if (lane == 63) wsum[wid] = v;
        __syncthreads();
        if (wid == 0) {
            u32 wv = (lane < 16) ? wsum[lane] : 0;
            for (int off = 1; off < 16; off <<= 1) {
                u32 x = __shfl_up(wv, off);
                if (lane >= off) wv += x;
            }
            if (lane < 16) wsum[lane] = wv;
        }
        __syncthreads();
        u32 incl = v + ((wid > 0) ? wsum[wid - 1] : 0) + carry_s;
        u32 excl = incl - h;
        if (t < KSEG) {
            Pb[(size_t)b * (KSEG + 1) + t] = (u16)excl;
            if (!(t & 1)) cp[t >> 1] = excl | (incl << 16);  // excl_t | excl_{t+1}<<16
            if (t == HALF) pb_half = excl;                   // phase-0 element count
        }
        __syncthreads();
        if (tid == 1023) carry_s = incl;
    }
    __syncthreads();
    u32 total = carry_s;
    if (tid == 0) Pb[(size_t)b * (KSEG + 1) + KSEG] = (u16)total;
    u32 base0 = pb_half;
    __syncthreads();

    // ---- two bin-range phases: LDS scatter then coalesced dump ----
    for (int ph = 0; ph < 2; ++ph) {
        int t0 = ph ? HALF : 0;
        u32 pbase = ph ? base0 : 0;
        u32 plen = ph ? (total - base0) : base0;
        for (int k = 0; k < kiter; ++k) {
            int d = myd[k];
            if ((unsigned)(d - t0) < (unsigned)HALF) {
                int j = s + tid + (k << 10);
                u32 add = (d & 1) ? 0x10000u : 1u;
                u32 old = atomicAdd(&cp[d >> 1], add);
                u32 pos = (d & 1) ? (old >> 16) : (old & 0xffffu);
                u32 hi = ((u32)j << 1) | (u32)events[j];
                rec[pos - pbase] = ((u64)hi << 32) | (u64)__float_as_uint(log_h[j]);
            }
        }
        __syncthreads();
        for (u32 i = tid; i < plen; i += 1024) S[(size_t)s + pbase + i] = rec[i];
        __syncthreads();
    }
}

// ---------------- counts[t] = sum_b (Pb[b][t+1]-Pb[b][t]) ----------------
__global__ void colscan_counts(const u16* __restrict__ Pb, int* __restrict__ counts) {
    int t = blockIdx.x * blockDim.x + threadIdx.x;
    if (t >= KSEG) return;
    int run = 0;
    for (int b = 0; b < NBLK; ++b) {
        const u16* row = Pb + (size_t)b * (KSEG + 1);
        run += (int)row[t + 1] - (int)row[t];
    }
    counts[t] = run;
}

// ---------------- exclusive prefix scan over K bins (single block) ----------------
__global__ void scan_kernel(const int* __restrict__ counts, int* __restrict__ cum, int K) {
    __shared__ int sm[1024];
    __shared__ int carry_s;
    int tid = threadIdx.x;
    if (tid == 0) carry_s = 0;
    __syncthreads();
    for (int base = 0; base < K; base += 1024) {
        int v = (base + tid < K) ? counts[base + tid] : 0;
        sm[tid] = v;
        __syncthreads();
        for (int off = 1; off < 1024; off <<= 1) {
            int t = (tid >= off) ? sm[tid - off] : 0;
            __syncthreads();
            sm[tid] += t;
            __syncthreads();
        }
        int carry = carry_s;
        if (base + tid < K) cum[base + tid] = carry + sm[tid] - v;  // exclusive
        __syncthreads();
        if (tid == 1023) carry_s = carry + sm[1023];
        __syncthreads();
    }
    if (tid == 0) cum[K] = carry_s;
}

// ---------------- transpose Pb[NBLK][K+1] -> PbT[K+1][NBLK] ----------------
__global__ void transpose_pb(const u16* __restrict__ Pb, u16* __restrict__ PbT) {
    __shared__ u16 tile[64][65];
    int t0 = blockIdx.x * 64;
    int b0 = blockIdx.y * 64;
    int tx = threadIdx.x;        // 0..63
    int ty = threadIdx.y;        // 0..3
    for (int r = ty; r < 64; r += 4) {
        int b = b0 + r, t = t0 + tx;
        tile[r][tx] = (b < NBLK && t <= KSEG) ? Pb[(size_t)b * (KSEG + 1) + t] : (u16)0;
    }
    __syncthreads();
    for (int r = ty; r < 64; r += 4) {
        int t = t0 + r, b = b0 + tx;
        if (t <= KSEG && b < NBLK) PbT[(size_t)t * NBLK + b] = tile[tx][r];
    }
}

// ---------------- per-bin-range (GBIN bins/block): contiguous gather, sort runs, emit ----
__global__ __launch_bounds__(256) void runsort_pe3(const u64* __restrict__ S,
                                                   const int* __restrict__ cum,
                                                   const u16* __restrict__ PbT,
                                                   float* __restrict__ P,
                                                   u32* __restrict__ J,
                                                   u32* __restrict__ E2w,
                                                   u16* __restrict__ binhint,
                                                   int N, int chunk) {
    __shared__ u64 sm[CAPE];                 // 65536 B
    __shared__ int L[GBIN * 256];            // 8192 B: run lens -> dest offsets
    __shared__ u16 rows[(GBIN + 1) * 256];   // 4608 B: PbT rows
    __shared__ int cumLoc[GBIN + 1];
    __shared__ u32 bits[128];
    __shared__ int t256[256];
    __shared__ u32 wpart[4];

    int t0 = blockIdx.x * GBIN;
    int G2 = min(GBIN, KSEG - t0);
    if (G2 <= 0) return;
    int tid = threadIdx.x;
    int lane = tid & 63, wid = tid >> 6;

    for (int t = 0; t <= G2; ++t)
        rows[t * 256 + tid] = PbT[(size_t)(t0 + t) * NBLK + tid];
    if (tid <= G2) cumLoc[tid] = cum[t0 + tid];
    __syncthreads();

    int u = 0;
    while (u < G2) {
        int m = 1;
        while (u + m < G2 && cumLoc[u + m + 1] - cumLoc[u] <= CAPE) ++m;
        int aBatch = cumLoc[u];

        // ---- run lengths into L (bin-major, block-minor), pad with 0 ----
        for (int tt = 0; tt < GBIN; ++tt) {
            int v = 0;
            if (tt < m)
                v = (int)rows[(u + tt + 1) * 256 + tid] - (int)rows[(u + tt) * 256 + tid];
            L[tt * 256 + tid] = v;
        }
        __syncthreads();

        // ---- exclusive scan of 2048 entries: 8-chains + one 256-scan ----
        int r8[8];
        int base8 = tid * 8, sum8 = 0;
        for (int k = 0; k < 8; ++k) { r8[k] = sum8; sum8 += L[base8 + k]; }
        t256[tid] = sum8;
        __syncthreads();
        {
            int v = t256[tid];
            for (int off = 1; off < 64; off <<= 1) {
                int x = __shfl_up(v, off);
                if (lane >= off) v += x;
            }
            if (lane == 63) wpart[wid] = (u32)v;
            __syncthreads();
            if (tid == 0) {
                u32 run = 0;
                for (int w = 0; w < 4; ++w) { u32 tmp = wpart[w]; wpart[w] = run; run += tmp; }
            }
            __syncthreads();
            int excl = v - sum8 + (int)wpart[wid];
            for (int k = 0; k < 8; ++k) r8[k] += excl;
        }
        __syncthreads();
        for (int k = 0; k < 8; ++k) L[base8 + k] = r8[k];
        __syncthreads();

        // ---- gather my contiguous S segment + insertion-sort each run ----
        {
            const u64* src = S + (size_t)tid * chunk + (int)rows[u * 256 + tid];
            for (int tt = 0; tt < m; ++tt) {
                int l = (int)rows[(u + tt + 1) * 256 + tid] - (int)rows[(u + tt) * 256 + tid];
                int o = L[tt * 256 + tid];
                for (int i = 0; i < l; ++i) sm[o + i] = src[i];
                src += l;
                for (int i = 1; i < l; ++i) {
                    u64 key = sm[o + i];
                    int jj = o + i - 1;
                    while (jj >= o && sm[jj] > key) { sm[jj + 1] = sm[jj]; --jj; }
                    sm[jj + 1] = key;
                }
            }
        }
        __syncthreads();

        // ---- emit per bin: P (desc), J (asc), E2 bitfield, binhint ----
        for (int tt = 0; tt < m; ++tt) {
            int t = u + tt;
            int a = cumLoc[t], b = cumLoc[t + 1];
            int c = b - a;
            int lbase = a - aBatch;
            int q0 = N - b;
            int nw = (c + 31) >> 5;
            for (int k = tid; k < nw; k += 256) bits[k] = 0;
            __syncthreads();
            for (int i = tid; i < c; i += 256) {
                u64 rec = sm[lbase + i];
                P[q0 + i] = expf(__uint_as_float((u32)rec));
                J[a + i] = (u32)(rec >> 33);
                if (rec & 0x100000000ull) atomicOr(&bits[i >> 5], 1u << (i & 31));
            }
            __syncthreads();
            for (int k = tid; k < nw; k += 256) {
                u32 v = bits[k];
                if (!v) continue;
                long gb = (long)q0 + 32l * k;
                int w = (int)(gb >> 5), sh = (int)(gb & 31);
                atomicOr(&E2w[w], v << sh);
                if (sh && (v >> (32 - sh))) atomicOr(&E2w[w + 1], v >> (32 - sh));
            }
            if (tid == 0) {
                // GLOBAL bin id in the hint (R10 bug: wrote local t -> mse4 walked ~10k bins)
                for (int k = (a + 255) >> 8; (k << 8) < b; ++k) binhint[k] = (u16)(t0 + t);
            }
            __syncthreads();
        }
        u += m;
    }
}

// ---------------- segment sums (faithful cross-indexing): keyed by dur[j], summand P[j] ----
__global__ __launch_bounds__(1024) void sums3(const int* __restrict__ dur,
                                              const float* __restrict__ P,
                                              const u32* __restrict__ E2w,
                                              float* __restrict__ expg_part,
                                              u16* __restrict__ evs_part,
                                              int N, int chunk) {
    __shared__ float he[KSEG];
    __shared__ int hv[KSEG];
    for (int i = threadIdx.x; i < KSEG; i += blockDim.x) { he[i] = 0.f; hv[i] = 0; }
    __syncthreads();
    int b = blockIdx.x;
    int s = b * chunk, e = min(N, s + chunk);
    for (int j = s + threadIdx.x; j < e; j += blockDim.x) {
        int t = dur[j];
        atomicAdd(&he[t], P[j]);
        if ((E2w[j >> 5] >> (j & 31)) & 1u) atomicAdd(&hv[t], 1);
    }
    __syncthreads();
    for (int i = threadIdx.x; i < KSEG; i += blockDim.x) {
        expg_part[(size_t)b * KSEG + i] = he[i];
        evs_part[(size_t)b * KSEG + i] = (u16)hv[i];
    }
}

__global__ void reduce_sums(const float* __restrict__ expg_part,
                            const u16* __restrict__ evs_part,
                            float* __restrict__ expg, float* __restrict__ evs, int B) {
    int t = blockIdx.x * blockDim.x + threadIdx.x;
    if (t >= KSEG) return;
    float a = 0.f;
    int v = 0;
    for (int b = 0; b < B; ++b) {
        a += expg_part[(size_t)b * KSEG + t];
        v += (int)evs_part[(size_t)b * KSEG + t];
    }
    expg[t] = a;
    evs[t] = (float)v;
}

// ---------------- risk suffix-sum + baseline hazard + total events ----------------
__global__ void baseline_kernel(const float* __restrict__ expg, const float* __restrict__ evs,
                                float* __restrict__ base, float* __restrict__ ev_total, int K) {
    __shared__ float sm[1024];
    __shared__ float carry_s;
    int tid = threadIdx.x;
    if (tid == 0) carry_s = 0.f;
    float evloc = 0.f;
    __syncthreads();
    for (int b = 0; b < K; b += 1024) {
        int u = b + tid;
        int t = K - 1 - u;
        float v = 0.f, ev = 0.f;
        if (u < K) { v = expg[t]; ev = evs[t]; }
        evloc += ev;
        sm[tid] = v;
        __syncthreads();
        for (int off = 1; off < 1024; off <<= 1) {
            float x = (tid >= off) ? sm[tid - off] : 0.f;
            __syncthreads();
            sm[tid] += x;
            __syncthreads();
        }
        float carry = carry_s;
        if (u < K) {
            float risk = carry + sm[tid];  // inclusive suffix sum over bins >= t
            base[t] = (risk > 0.f) ? ev / risk : 0.f;
        }
        __syncthreads();
        if (tid == 1023) carry_s = carry + sm[1023];
        __syncthreads();
    }
    sm[tid] = evloc;
    __syncthreads();
    for (int o = 512; o > 0; o >>= 1) {
        if (tid < o) sm[tid] += sm[tid + o];
        __syncthreads();
    }
    if (tid == 0) ev_total[0] = sm[0];
}

// ---------------- MSE, flat grid-stride: (base[t(i)]*P[i] - E2bit[J[i]])^2 ----------------
__global__ __launch_bounds__(1024) void mse4(const float* __restrict__ P,
                                             const u32* __restrict__ J,
                                             const u32* __restrict__ E2w,
                                             const int* __restrict__ cum,
                                             const u16* __restrict__ binhint,
                                             const float* __restrict__ base,
                                             double* __restrict__ acc, int N) {
    int stride = gridDim.x * blockDim.x;
    double s = 0.0;
    for (int i = blockIdx.x * blockDim.x + threadIdx.x; i < N; i += stride) {
        int t = (int)binhint[i >> 8];
        while (cum[t + 1] <= i) ++t;
        u32 x = J[i];
        float ev = (float)((E2w[x >> 5] >> (x & 31)) & 1u);
        float d = base[t] * P[i] - ev;
        s += (double)d * (double)d;
    }
    __shared__ double sm[1024];
    sm[threadIdx.x] = s;
    __syncthreads();
    for (int o = 512; o > 0; o >>= 1) {
        if ((int)threadIdx.x < o) sm[threadIdx.x] += sm[threadIdx.x + o];
        __syncthreads();
    }
    if (threadIdx.x == 0) atomicAdd(acc, sm[0]);
}

__global__ void final_kernel(const double* __restrict__ acc, const float* __restrict__ ev_total,
                             float* __restrict__ out, int N) {
    out[0] = (ev_total[0] == 0.f) ? 0.0f : (float)(*acc / (double)N);
}

extern "C" void kernel_launch(void* const* d_in, const int* in_sizes, int n_in,
                              void* d_out, int out_size, void* d_ws, size_t ws_size,
                              hipStream_t stream) {
    const float* log_h = (const float*)d_in[0];
    const int* dur     = (const int*)d_in[1];
    const int* events  = (const int*)d_in[2];
    int N = in_sizes[0];
    float* out = (float*)d_out;

    char* ws = (char*)d_ws;
    size_t off = 0;
    auto alloc = [&](size_t bytes) -> char* {
        char* p = ws + off;
        off = (off + bytes + 255) & ~(size_t)255;
        return p;
    };
    double* acc  = (double*)alloc(8);
    u32*    E2w  = (u32*)alloc(((size_t)N / 32 + 2) * 4);   // event bitfield (desc-indexed)
    size_t zero_bytes = off;                                 // acc + E2w must start at 0
    float*  ev_total = (float*)alloc(4);
    int*    counts   = (int*)alloc(KSEG * 4);
    int*    cum      = (int*)alloc((KSEG + 1) * 4);
    float*  expg     = (float*)alloc(KSEG * 4);
    float*  evs      = (float*)alloc(KSEG * 4);
    float*  base     = (float*)alloc(KSEG * 4);
    u16*    binhint  = (u16*)alloc(((size_t)N / 256 + 1) * 2);
    u16*    Pb       = (u16*)alloc((size_t)NBLK * (KSEG + 1) * 2);
    u16*    PbT      = (u16*)alloc((size_t)(KSEG + 1) * NBLK * 2);
    u64*    S        = (u64*)alloc((size_t)N * 8);
    float*  P        = (float*)alloc((size_t)N * 4);
    u32*    J        = (u32*)alloc((size_t)N * 4);
    (void)ws_size;

    // sums partials alias S (dead after runsort_pe3; mse4 uses P/J, not S)
    float* expg_part = (float*)S;
    u16*   evs_part  = (u16*)((char*)S + (size_t)NBLK * KSEG * 4 + 256);

    int chunk = (N + NBLK - 1) / NBLK;   // 31250 < 65536 -> u16 offsets valid

    hipMemsetAsync(d_ws, 0, zero_bytes, stream);

    localsort_lds<<<NBLK, 1024, 0, stream>>>(dur, log_h, events, S, Pb, N, chunk);
    colscan_counts<<<(KSEG + 255) / 256, 256, 0, stream>>>(Pb, counts);
    scan_kernel<<<1, 1024, 0, stream>>>(counts, cum, KSEG);
    transpose_pb<<<dim3((KSEG + 64) / 64, NBLK / 64), dim3(64, 4), 0, stream>>>(Pb, PbT);
    runsort_pe3<<<(KSEG + GBIN - 1) / GBIN, 256, 0, stream>>>(S, cum, PbT, P, J, E2w,
                                                              binhint, N, chunk);
    sums3<<<NBLK, 1024, 0, stream>>>(dur, P, E2w, expg_part, evs_part, N, chunk);
    reduce_sums<<<(KSEG + 255) / 256, 256, 0, stream>>>(expg_part, evs_part, expg, evs, NBLK);
    baseline_kernel<<<1, 1024, 0, stream>>>(expg, evs, base, ev_total, KSEG);
    mse4<<<512, 1024, 0, stream>>>(P, J, E2w, cum, binhint, base, acc, N);
    final_kernel<<<1, 1, 0, stream>>>(acc, ev_total, out, N);
}

// Round 12
// 494.229 us; speedup vs baseline: 13.4029x; 1.0628x over previous
//
#include <hip/hip_runtime.h>

#define KSEG 10000
#define NBLK 256          // counting-sort blocks == CUs; chunk = 31250
#define HALF 5000         // bin-range phase split
#define RECMAX 17000      // LDS record capacity per phase (Binom(31250,.5): +15 sigma)
#define GBIN 8            // bins per runsort block
#define CAPE 8192         // runsort staging capacity (mean 6400, +22 sigma)

typedef unsigned long long u64;
typedef unsigned int u32;
typedef unsigned short u16;
typedef unsigned char u8;

// ---------------- fused: hist + per-block scan + LDS-staged counting scatter ----------------
__global__ __launch_bounds__(1024) void localsort_lds(const int* __restrict__ dur,
                                                      const float* __restrict__ log_h,
                                                      const int* __restrict__ events,
                                                      u64* __restrict__ S,
                                                      u16* __restrict__ Pb,
                                                      int N, int chunk) {
    __shared__ u64 rec[RECMAX];          // 136000 B (phase staging; overlaid by h32 early)
    __shared__ u32 cp[KSEG / 2];         // 20000 B packed dual-u16 cursors
    __shared__ u32 wsum[16];
    __shared__ u32 carry_s, pb_half;
    u32* h32 = (u32*)rec;                // 40000 B overlay, dead before rec is written

    int b = blockIdx.x;
    int s = b * chunk, e = min(N, s + chunk);
    int tid = threadIdx.x;
    int lane = tid & 63, wid = tid >> 6;
    int kiter = (chunk + 1023) >> 10;    // 31 for N=8M

    for (int i = tid; i < KSEG; i += 1024) h32[i] = 0;
    if (tid == 0) carry_s = 0;
    __syncthreads();

    // ---- read dur into regs + histogram ----
    int myd[32];
    for (int k = 0; k < kiter; ++k) {
        int j = s + tid + (k << 10);
        int d = -1;
        if (j < e) { d = dur[j]; atomicAdd(&h32[d], 1); }
        myd[k] = d;
    }
    __syncthreads();

    // ---- exclusive scan over KSEG bins (strips of 1024, wave-shuffle scan) ----
    for (int base = 0; base < KSEG; base += 1024) {
        int t = base + tid;
        u32 h = (t < KSEG) ? h32[t] : 0;
        u32 v = h;
        for (int off = 1; off < 64; off <<= 1) {
            u32 x = __shfl_up(v, off);
            if (lane >= off) v += x;
        }
        if (lane == 63) wsum[wid] = v;
        __syncthreads();
        if (wid == 0) {
            u32 wv = (lane < 16) ? wsum[lane] : 0;
            for (int off = 1; off < 16; off <<= 1) {
                u32 x = __shfl_up(wv, off);
                if (lane >= off) wv += x;
            }
            if (lane < 16) wsum[lane] = wv;
        }
        __syncthreads();
        u32 incl = v + ((wid > 0) ? wsum[wid - 1] : 0) + carry_s;
        u32 excl = incl - h;
        if (t < KSEG) {
            Pb[(size_t)b * (KSEG + 1) + t] = (u16)excl;
            if (!(t & 1)) cp[t >> 1] = excl | (incl << 16);  // excl_t | excl_{t+1}<<16
            if (t == HALF) pb_half = excl;                   // phase-0 element count
        }
        __syncthreads();
        if (tid == 1023) carry_s = incl;
    }
    __syncthreads();
    u32 total = carry_s;
    if (tid == 0) Pb[(size_t)b * (KSEG + 1) + KSEG] = (u16)total;
    u32 base0 = pb_half;
    __syncthreads();

    // ---- two bin-range phases: LDS scatter then coalesced dump ----
    for (int ph = 0; ph < 2; ++ph) {
        int t0 = ph ? HALF : 0;
        u32 pbase = ph ? base0 : 0;
        u32 plen = ph ? (total - base0) : base0;
        for (int k = 0; k < kiter; ++k) {
            int d = myd[k];
            if ((unsigned)(d - t0) < (unsigned)HALF) {
                int j = s + tid + (k << 10);
                u32 add = (d & 1) ? 0x10000u : 1u;
                u32 old = atomicAdd(&cp[d >> 1], add);
                u32 pos = (d & 1) ? (old >> 16) : (old & 0xffffu);
                u32 hi = ((u32)j << 1) | (u32)events[j];
                rec[pos - pbase] = ((u64)hi << 32) | (u64)__float_as_uint(log_h[j]);
            }
        }
        __syncthreads();
        for (u32 i = tid; i < plen; i += 1024) S[(size_t)s + pbase + i] = rec[i];
        __syncthreads();
    }
}

// ---------------- counts[t] = sum_b (Pb[b][t+1]-Pb[b][t]) ----------------
__global__ void colscan_counts(const u16* __restrict__ Pb, int* __restrict__ counts) {
    int t = blockIdx.x * blockDim.x + threadIdx.x;
    if (t >= KSEG) return;
    int run = 0;
    for (int b = 0; b < NBLK; ++b) {
        const u16* row = Pb + (size_t)b * (KSEG + 1);
        run += (int)row[t + 1] - (int)row[t];
    }
    counts[t] = run;
}

// ---------------- exclusive prefix scan over K bins (single block) ----------------
__global__ void scan_kernel(const int* __restrict__ counts, int* __restrict__ cum, int K) {
    __shared__ int sm[1024];
    __shared__ int carry_s;
    int tid = threadIdx.x;
    if (tid == 0) carry_s = 0;
    __syncthreads();
    for (int base = 0; base < K; base += 1024) {
        int v = (base + tid < K) ? counts[base + tid] : 0;
        sm[tid] = v;
        __syncthreads();
        for (int off = 1; off < 1024; off <<= 1) {
            int t = (tid >= off) ? sm[tid - off] : 0;
            __syncthreads();
            sm[tid] += t;
            __syncthreads();
        }
        int carry = carry_s;
        if (base + tid < K) cum[base + tid] = carry + sm[tid] - v;  // exclusive
        __syncthreads();
        if (tid == 1023) carry_s = carry + sm[1023];
        __syncthreads();
    }
    if (tid == 0) cum[K] = carry_s;
}

// ---------------- transpose Pb[NBLK][K+1] -> PbT[K+1][NBLK] ----------------
__global__ void transpose_pb(const u16* __restrict__ Pb, u16* __restrict__ PbT) {
    __shared__ u16 tile[64][65];
    int t0 = blockIdx.x * 64;
    int b0 = blockIdx.y * 64;
    int tx = threadIdx.x;        // 0..63
    int ty = threadIdx.y;        // 0..3
    for (int r = ty; r < 64; r += 4) {
        int b = b0 + r, t = t0 + tx;
        tile[r][tx] = (b < NBLK && t <= KSEG) ? Pb[(size_t)b * (KSEG + 1) + t] : (u16)0;
    }
    __syncthreads();
    for (int r = ty; r < 64; r += 4) {
        int t = t0 + r, b = b0 + tx;
        if (t <= KSEG && b < NBLK) PbT[(size_t)t * NBLK + b] = tile[tx][r];
    }
}

// ---------------- per-bin-range (GBIN bins/block, 512 thr): pair-parallel gather+sort ----
// Work unit = (bin tt, source block b): one tiny run (mean ~3.1). 2048 pairs / 512 threads.
__global__ __launch_bounds__(512) void runsort_pe4(const u64* __restrict__ S,
                                                   const int* __restrict__ cum,
                                                   const u16* __restrict__ PbT,
                                                   float* __restrict__ P,
                                                   u32* __restrict__ J,
                                                   u32* __restrict__ E2w,
                                                   u16* __restrict__ binhint,
                                                   int N, int chunk) {
    __shared__ u64 sm[CAPE];                 // 65536 B
    __shared__ int L[GBIN * 256];            // 8192 B: run lens -> dest offsets
    __shared__ u16 rows[(GBIN + 1) * 256];   // 4608 B: PbT rows (absolute per-block offsets)
    __shared__ int t512[512];                // 2048 B scan partials
    __shared__ int cumLoc[GBIN + 1];
    __shared__ u32 bits[128];
    __shared__ u32 wpart[8];

    int t0 = blockIdx.x * GBIN;
    int G2 = min(GBIN, KSEG - t0);
    if (G2 <= 0) return;
    int tid = threadIdx.x;
    int lane = tid & 63, wid = tid >> 6;

    for (int i = tid; i < (G2 + 1) * 256; i += 512) {
        int t = i >> 8, b = i & 255;
        rows[i] = PbT[(size_t)(t0 + t) * NBLK + b];
    }
    if (tid <= G2) cumLoc[tid] = cum[t0 + tid];
    __syncthreads();

    int u = 0;
    while (u < G2) {
        int m = 1;
        while (u + m < G2 && cumLoc[u + m + 1] - cumLoc[u] <= CAPE) ++m;
        int aBatch = cumLoc[u];

        // ---- run lengths into L (bin-major, block-minor), pad with 0 ----
        for (int i = tid; i < GBIN * 256; i += 512) {
            int tt = i >> 8, b = i & 255;
            int v = 0;
            if (tt < m)
                v = (int)rows[(u + tt + 1) * 256 + b] - (int)rows[(u + tt) * 256 + b];
            L[i] = v;
        }
        __syncthreads();

        // ---- exclusive scan of 2048 entries: 4-chains + one 512-thread scan ----
        int r4[4];
        int base4 = tid * 4, sum4 = 0;
        for (int k = 0; k < 4; ++k) { r4[k] = sum4; sum4 += L[base4 + k]; }
        t512[tid] = sum4;
        __syncthreads();
        {
            int v = t512[tid];
            for (int off = 1; off < 64; off <<= 1) {
                int x = __shfl_up(v, off);
                if (lane >= off) v += x;
            }
            if (lane == 63) wpart[wid] = (u32)v;
            __syncthreads();
            if (tid == 0) {
                u32 run = 0;
                for (int w = 0; w < 8; ++w) { u32 tmp = wpart[w]; wpart[w] = run; run += tmp; }
            }
            __syncthreads();
            int excl = v - sum4 + (int)wpart[wid];
            for (int k = 0; k < 4; ++k) r4[k] += excl;
        }
        __syncthreads();
        for (int k = 0; k < 4; ++k) L[base4 + k] = r4[k];
        __syncthreads();

        // ---- pair-parallel gather + insertion-sort: pair = (tt, b) ----
        for (int i = tid; i < m * 256; i += 512) {
            int tt = i >> 8, b = i & 255;
            int r0 = (int)rows[(u + tt) * 256 + b];
            int l = (int)rows[(u + tt + 1) * 256 + b] - r0;
            int o = L[i];
            const u64* src = S + (size_t)b * chunk + r0;
            for (int k = 0; k < l; ++k) sm[o + k] = src[k];
            for (int k = 1; k < l; ++k) {
                u64 key = sm[o + k];
                int jj = o + k - 1;
                while (jj >= o && sm[jj] > key) { sm[jj + 1] = sm[jj]; --jj; }
                sm[jj + 1] = key;
            }
        }
        __syncthreads();

        // ---- emit per bin: P (desc), J (asc), E2 bitfield, binhint ----
        for (int tt = 0; tt < m; ++tt) {
            int t = u + tt;
            int a = cumLoc[t], b = cumLoc[t + 1];
            int c = b - a;
            int lbase = a - aBatch;
            int q0 = N - b;
            int nw = (c + 31) >> 5;
            for (int k = tid; k < nw; k += 512) bits[k] = 0;
            __syncthreads();
            for (int i = tid; i < c; i += 512) {
                u64 rec = sm[lbase + i];
                P[q0 + i] = expf(__uint_as_float((u32)rec));
                J[a + i] = (u32)(rec >> 33);
                if (rec & 0x100000000ull) atomicOr(&bits[i >> 5], 1u << (i & 31));
            }
            __syncthreads();
            for (int k = tid; k < nw; k += 512) {
                u32 v = bits[k];
                if (!v) continue;
                long gb = (long)q0 + 32l * k;
                int w = (int)(gb >> 5), sh = (int)(gb & 31);
                atomicOr(&E2w[w], v << sh);
                if (sh && (v >> (32 - sh))) atomicOr(&E2w[w + 1], v >> (32 - sh));
            }
            if (tid == 0) {
                // GLOBAL bin id (R10 bug was local id)
                for (int k = (a + 255) >> 8; (k << 8) < b; ++k) binhint[k] = (u16)(t0 + t);
            }
            __syncthreads();
        }
        u += m;
    }
}

// ---------------- segment sums (faithful cross-indexing): keyed by dur[j], summand P[j] ----
__global__ __launch_bounds__(1024) void sums3(const int* __restrict__ dur,
                                              const float* __restrict__ P,
                                              const u32* __restrict__ E2w,
                                              float* __restrict__ expg_part,
                                              u16* __restrict__ evs_part,
                                              int N, int chunk) {
    __shared__ float he[KSEG];
    __shared__ int hv[KSEG];
    for (int i = threadIdx.x; i < KSEG; i += blockDim.x) { he[i] = 0.f; hv[i] = 0; }
    __syncthreads();
    int b = blockIdx.x;
    int s = b * chunk, e = min(N, s + chunk);
    for (int j = s + threadIdx.x; j < e; j += blockDim.x) {
        int t = dur[j];
        atomicAdd(&he[t], P[j]);
        if ((E2w[j >> 5] >> (j & 31)) & 1u) atomicAdd(&hv[t], 1);
    }
    __syncthreads();
    for (int i = threadIdx.x; i < KSEG; i += blockDim.x) {
        expg_part[(size_t)b * KSEG + i] = he[i];
        evs_part[(size_t)b * KSEG + i] = (u16)hv[i];
    }
}

__global__ void reduce_sums(const float* __restrict__ expg_part,
                            const u16* __restrict__ evs_part,
                            float* __restrict__ expg, float* __restrict__ evs, int B) {
    int t = blockIdx.x * blockDim.x + threadIdx.x;
    if (t >= KSEG) return;
    float a = 0.f;
    int v = 0;
    for (int b = 0; b < B; ++b) {
        a += expg_part[(size_t)b * KSEG + t];
        v += (int)evs_part[(size_t)b * KSEG + t];
    }
    expg[t] = a;
    evs[t] = (float)v;
}

// ---------------- risk suffix-sum + baseline hazard + total events ----------------
__global__ void baseline_kernel(const float* __restrict__ expg, const float* __restrict__ evs,
                                float* __restrict__ base, float* __restrict__ ev_total, int K) {
    __shared__ float sm[1024];
    __shared__ float carry_s;
    int tid = threadIdx.x;
    if (tid == 0) carry_s = 0.f;
    float evloc = 0.f;
    __syncthreads();
    for (int b = 0; b < K; b += 1024) {
        int u = b + tid;
        int t = K - 1 - u;
        float v = 0.f, ev = 0.f;
        if (u < K) { v = expg[t]; ev = evs[t]; }
        evloc += ev;
        sm[tid] = v;
        __syncthreads();
        for (int off = 1; off < 1024; off <<= 1) {
            float x = (tid >= off) ? sm[tid - off] : 0.f;
            __syncthreads();
            sm[tid] += x;
            __syncthreads();
        }
        float carry = carry_s;
        if (u < K) {
            float risk = carry + sm[tid];  // inclusive suffix sum over bins >= t
            base[t] = (risk > 0.f) ? ev / risk : 0.f;
        }
        __syncthreads();
        if (tid == 1023) carry_s = carry + sm[1023];
        __syncthreads();
    }
    sm[tid] = evloc;
    __syncthreads();
    for (int o = 512; o > 0; o >>= 1) {
        if (tid < o) sm[tid] += sm[tid + o];
        __syncthreads();
    }
    if (tid == 0) ev_total[0] = sm[0];
}

// ---------------- MSE, flat grid-stride: (base[t(i)]*P[i] - E2bit[J[i]])^2 ----------------
__global__ __launch_bounds__(1024) void mse4(const float* __restrict__ P,
                                             const u32* __restrict__ J,
                                             const u32* __restrict__ E2w,
                                             const int* __restrict__ cum,
                                             const u16* __restrict__ binhint,
                                             const float* __restrict__ base,
                                             double* __restrict__ acc, int N) {
    int stride = gridDim.x * blockDim.x;
    double s = 0.0;
    for (int i = blockIdx.x * blockDim.x + threadIdx.x; i < N; i += stride) {
        int t = (int)binhint[i >> 8];
        while (cum[t + 1] <= i) ++t;
        u32 x = J[i];
        float ev = (float)((E2w[x >> 5] >> (x & 31)) & 1u);
        float d = base[t] * P[i] - ev;
        s += (double)d * (double)d;
    }
    __shared__ double sm[1024];
    sm[threadIdx.x] = s;
    __syncthreads();
    for (int o = 512; o > 0; o >>= 1) {
        if ((int)threadIdx.x < o) sm[threadIdx.x] += sm[threadIdx.x + o];
        __syncthreads();
    }
    if (threadIdx.x == 0) atomicAdd(acc, sm[0]);
}

__global__ void final_kernel(const double* __restrict__ acc, const float* __restrict__ ev_total,
                             float* __restrict__ out, int N) {
    out[0] = (ev_total[0] == 0.f) ? 0.0f : (float)(*acc / (double)N);
}

extern "C" void kernel_launch(void* const* d_in, const int* in_sizes, int n_in,
                              void* d_out, int out_size, void* d_ws, size_t ws_size,
                              hipStream_t stream) {
    const float* log_h = (const float*)d_in[0];
    const int* dur     = (const int*)d_in[1];
    const int* events  = (const int*)d_in[2];
    int N = in_sizes[0];
    float* out = (float*)d_out;

    char* ws = (char*)d_ws;
    size_t off = 0;
    auto alloc = [&](size_t bytes) -> char* {
        char* p = ws + off;
        off = (off + bytes + 255) & ~(size_t)255;
        return p;
    };
    double* acc  = (double*)alloc(8);
    u32*    E2w  = (u32*)alloc(((size_t)N / 32 + 2) * 4);   // event bitfield (desc-indexed)
    size_t zero_bytes = off;                                 // acc + E2w must start at 0
    float*  ev_total = (float*)alloc(4);
    int*    counts   = (int*)alloc(KSEG * 4);
    int*    cum      = (int*)alloc((KSEG + 1) * 4);
    float*  expg     = (float*)alloc(KSEG * 4);
    float*  evs      = (float*)alloc(KSEG * 4);
    float*  base     = (float*)alloc(KSEG * 4);
    u16*    binhint  = (u16*)alloc(((size_t)N / 256 + 1) * 2);
    u16*    Pb       = (u16*)alloc((size_t)NBLK * (KSEG + 1) * 2);
    u16*    PbT      = (u16*)alloc((size_t)(KSEG + 1) * NBLK * 2);
    u64*    S        = (u64*)alloc((size_t)N * 8);
    float*  P        = (float*)alloc((size_t)N * 4);
    u32*    J        = (u32*)alloc((size_t)N * 4);
    (void)ws_size;

    // sums partials alias S (dead after runsort_pe4; mse4 uses P/J, not S)
    float* expg_part = (float*)S;
    u16*   evs_part  = (u16*)((char*)S + (size_t)NBLK * KSEG * 4 + 256);

    int chunk = (N + NBLK - 1) / NBLK;   // 31250 < 65536 -> u16 offsets valid

    hipMemsetAsync(d_ws, 0, zero_bytes, stream);

    localsort_lds<<<NBLK, 1024, 0, stream>>>(dur, log_h, events, S, Pb, N, chunk);
    colscan_counts<<<(KSEG + 255) / 256, 256, 0, stream>>>(Pb, counts);
    scan_kernel<<<1, 1024, 0, stream>>>(counts, cum, KSEG);
    transpose_pb<<<dim3((KSEG + 64) / 64, NBLK / 64), dim3(64, 4), 0, stream>>>(Pb, PbT);
    runsort_pe4<<<(KSEG + GBIN - 1) / GBIN, 512, 0, stream>>>(S, cum, PbT, P, J, E2w,
                                                              binhint, N, chunk);
    sums3<<<NBLK, 1024, 0, stream>>>(dur, P, E2w, expg_part, evs_part, N, chunk);
    reduce_sums<<<(KSEG + 255) / 256, 256, 0, stream>>>(expg_part, evs_part, expg, evs, NBLK);
    baseline_kernel<<<1, 1024, 0, stream>>>(expg, evs, base, ev_total, KSEG);
    mse4<<<512, 1024, 0, stream>>>(P, J, E2w, cum, binhint, base, acc, N);
    final_kernel<<<1, 1, 0, stream>>>(acc, ev_total, out, N);
}